// Round 5
// baseline (186.172 us; speedup 1.0000x reference)
//
#include <hip/hip_runtime.h>

#define NS 32768
#define NC 395
#define FD 512
#define NEL (NC * FD)

#define RS 16                  // row splits
#define CT 16                  // column tiles (32 floats each)
#define COLS 32
#define CF4 8                  // float4 per column tile
#define ROWS_PB (NS / RS)      // 2048 rows per block
#define NW 8                   // waves per block
#define LCAP 384               // per-wave list capacity (mean 256, +8.5 sigma)

// Static device scratch — every slot rewritten each call.
__device__ float g_part[2 * RS * NC * FD];   // [mod][rs][cls][FD] 25.9 MB
__device__ int   g_hist[RS * NC];

// ---------------------------------------------------------------------------
// K1: streaming segment-sum, no atomics. Block = (rs, mod, ct) covers rows
// [rs*2048,+2048) x cols [ct*32,+32). Wave w owns classes (c&7)==w and
// compacts its rows into a list (ballot/popcount). Main loop: ONE
// global_load_dwordx4 moves 8 rows x 128B = 1KB (lane: row r=lane>>3,
// f4-col c4=lane&7). Duplicate classes within a group are handled by
// rank-serialized RMW: row's rank = #earlier same-class rows in group
// (shfl_up compares); RMW executes in rank order (wave-serial => exact).
// acc4 bank swizzle (c4 + cls>>3)&7 decorrelates the 8 rows' b128 phases.
__global__ __launch_bounds__(512, 4)
void k_stream(const float* __restrict__ m1, const float* __restrict__ m2,
              const int* __restrict__ targets, float* __restrict__ out)
{
    const int bid = blockIdx.x;
    const int ct  = bid & (CT - 1);
    const int mod = (bid >> 4) & 1;
    const int rs  = bid >> 5;
    const int t   = threadIdx.x;
    const int w   = t >> 6;
    const int lane = t & 63;
    const int r    = lane >> 3;   // sub-row within group (0..7)
    const int c4   = lane & 7;    // float4 within column tile

    __shared__ float4 acc4[NC * CF4];     // 50,560 B
    __shared__ int    lists[NW * LCAP];   // 12,288 B  (total 62.8 KB)

    {
        float4 z = make_float4(0.f, 0.f, 0.f, 0.f);
        for (int i = t; i < NC * CF4; i += 512) acc4[i] = z;
    }
    if (bid == 0 && t == 0) out[0] = 0.f;   // zero before k_loss

    // ---- per-wave compaction: packed idx | cls<<12 (no atomics) ----
    const int* tgt = targets + rs * ROWS_PB;   // 8 KB, L1/L2-hot
    int* mylist = &lists[w * LCAP];
    int cnt = 0;
    int nxt = tgt[lane];
    for (int it = 0; it < ROWS_PB / 64; ++it) {
        int c = nxt;
        if (it + 1 < ROWS_PB / 64) nxt = tgt[(it + 1) * 64 + lane];
        bool pred = ((c & 7) == w);
        unsigned long long mask = __ballot(pred);
        int pos = (int)__popcll(mask & ((1ull << lane) - 1ull));
        if (pred && cnt + pos < LCAP)
            mylist[cnt + pos] = (it * 64 + lane) | (c << 12);
        cnt += (int)__popcll(mask);
    }
    if (cnt > LCAP) cnt = LCAP;   // unreachable for uniform targets
    __syncthreads();              // acc zero-init + lists complete

    // ---- main loop: 1 KB per load instruction, 4 groups in flight ----
    const float4* sp = reinterpret_cast<const float4*>(
        (mod ? m2 : m1) + (size_t)rs * ROWS_PB * FD) + ct * CF4 + c4;
    const int ngroups = (cnt + 7) >> 3;

#define LOADG(CLS, V, G)                                                 \
    {   int g_ = (G);                                                    \
        CLS = -1; V = make_float4(0.f, 0.f, 0.f, 0.f);                   \
        if (g_ < ngroups) {                                              \
            int e_   = mylist[g_ * 8 + r];      /* broadcast ds_read */  \
            bool a_  = (g_ * 8 + r) < cnt;                               \
            int idx_ = a_ ? (e_ & 0xFFF) : 0;                            \
            CLS      = a_ ? (e_ >> 12) : -1;                             \
            V        = sp[idx_ * 128];          /* 64 lanes = 1 KB   */  \
        }                                                                \
    }

#define RMWG(CLS, V)                                                     \
    {   int cls_ = CLS;                                                  \
        int rank_ = 0;                                                   \
        _Pragma("unroll")                                                \
        for (int d_ = 1; d_ < 8; ++d_) {                                 \
            int cu_ = __shfl_up(cls_, 8 * d_, 64);                       \
            rank_ += (r >= d_ && cu_ == cls_) ? 1 : 0;                   \
        }                                                                \
        for (int k_ = 0; k_ < 8; ++k_) {                                 \
            if (k_ > 0 && !__any(rank_ >= k_)) break;                    \
            if (cls_ >= 0 && rank_ == k_) {                              \
                int a_ = cls_ * 8 + ((c4 + (cls_ >> 3)) & 7);            \
                float4 o_ = acc4[a_];                                    \
                o_.x += V.x; o_.y += V.y; o_.z += V.z; o_.w += V.w;      \
                acc4[a_] = o_;                                           \
            }                                                            \
        }                                                                \
    }

    int cls0, cls1, cls2, cls3, cn0, cn1, cn2, cn3;
    float4 v0, v1, v2, v3, u0, u1, u2, u3;

    LOADG(cls0, v0, 0) LOADG(cls1, v1, 1) LOADG(cls2, v2, 2) LOADG(cls3, v3, 3)
    const int nbat = (ngroups + 3) >> 2;
    for (int b = 1; b < nbat; ++b) {
        int gb = b << 2;
        LOADG(cn0, u0, gb)     LOADG(cn1, u1, gb + 1)
        LOADG(cn2, u2, gb + 2) LOADG(cn3, u3, gb + 3)
        RMWG(cls0, v0) RMWG(cls1, v1) RMWG(cls2, v2) RMWG(cls3, v3)
        cls0 = cn0; v0 = u0; cls1 = cn1; v1 = u1;
        cls2 = cn2; v2 = u2; cls3 = cn3; v3 = u3;
    }
    RMWG(cls0, v0) RMWG(cls1, v1) RMWG(cls2, v2) RMWG(cls3, v3)
#undef LOADG
#undef RMWG
    __syncthreads();

    // ---- writeout (undo swizzle): acc4 -> g_part[(mod*RS+rs)][cls][ct*32..] ----
    float4* dst = reinterpret_cast<float4*>(g_part)
                + (size_t)(mod * RS + rs) * (NEL / 4) + ct * CF4;
    for (int i = t; i < NC * CF4; i += 512) {
        int cls = i >> 3, cc = i & 7;
        float4 vv = acc4[cls * 8 + ((cc + (cls >> 3)) & 7)];
        dst[(size_t)cls * (FD / 4) + cc] = vv;
    }

    // ---- fold histogram: one block per row-split (LDS reused) ----
    if (ct == 0 && mod == 0) {   // block-uniform condition: barriers legal
        __syncthreads();
        int* h = reinterpret_cast<int*>(acc4);
        for (int i = t; i < NC; i += 512) h[i] = 0;
        __syncthreads();
        for (int i = t; i < ROWS_PB; i += 512) atomicAdd(&h[tgt[i]], 1);
        __syncthreads();
        for (int i = t; i < NC; i += 512) g_hist[rs * NC + i] = h[i];
    }
}

// ---------------------------------------------------------------------------
__device__ __forceinline__ float smooth_l1(float d) {
    d = fabsf(d);
    return d < 1.0f ? 0.5f * d * d : d - 0.5f;
}

__device__ __forceinline__ void f4add(float4& a, const float4 b) {
    a.x += b.x; a.y += b.y; a.z += b.z; a.w += b.w;
}

// K2: combine RS partials per modality, SmoothL1 weighted by count, reduce.
__global__ __launch_bounds__(256)
void k_loss(const float* __restrict__ centers, float* __restrict__ out) {
    __shared__ float scnt[NC];
    int t = threadIdx.x;
    for (int c = t; c < NC; c += 256) {
        int s = 0;
        #pragma unroll
        for (int k = 0; k < RS; ++k) s += g_hist[k * NC + c];
        scnt[c] = (float)s;
    }
    __syncthreads();

    const float4* ctr4  = reinterpret_cast<const float4*>(centers);
    const float4* part4 = reinterpret_cast<const float4*>(g_part);
    const int NE4 = NEL / 4;          // 50560
    float val = 0.f;
    for (int g = blockIdx.x * 256 + t; g < NE4; g += gridDim.x * 256) {
        int cls = g >> 7;             // 128 float4 per class
        float cnt = scnt[cls];
        if (cnt > 0.f) {
            float4 s1 = make_float4(0,0,0,0), s2 = make_float4(0,0,0,0);
            #pragma unroll
            for (int k = 0; k < RS; ++k) {
                f4add(s1, part4[(size_t)k        * NE4 + g]);
                f4add(s2, part4[(size_t)(RS + k) * NE4 + g]);
            }
            float4 c4 = ctr4[g];
            float inv = 1.f / cnt;
            val += cnt * (smooth_l1(s1.x * inv - c4.x) + smooth_l1(s2.x * inv - c4.x)
                        + smooth_l1(s1.y * inv - c4.y) + smooth_l1(s2.y * inv - c4.y)
                        + smooth_l1(s1.z * inv - c4.z) + smooth_l1(s2.z * inv - c4.z)
                        + smooth_l1(s1.w * inv - c4.w) + smooth_l1(s2.w * inv - c4.w));
        }
    }

    for (int off = 32; off > 0; off >>= 1)
        val += __shfl_down(val, off, 64);
    __shared__ float wsum[4];
    int lane = t & 63, wid = t >> 6;
    if (lane == 0) wsum[wid] = val;
    __syncthreads();
    if (t == 0) {
        float sm = wsum[0] + wsum[1] + wsum[2] + wsum[3];
        atomicAdd(out, sm * 5.9604644775390625e-08f);  // 1/(N*D) = 2^-24
    }
}

extern "C" void kernel_launch(void* const* d_in, const int* in_sizes, int n_in,
                              void* d_out, int out_size, void* d_ws, size_t ws_size,
                              hipStream_t stream) {
    const float* m1 = (const float*)d_in[0];
    const float* m2 = (const float*)d_in[1];
    const float* centers = (const float*)d_in[2];
    const int* targets = (const int*)d_in[3];
    float* out = (float*)d_out;

    k_stream<<<RS * 2 * CT, 512, 0, stream>>>(m1, m2, targets, out);
    k_loss<<<400, 256, 0, stream>>>(centers, out);
}